// Round 4
// baseline (960.923 us; speedup 1.0000x reference)
//
#include <hip/hip_runtime.h>
#include <hip/hip_bf16.h>

// CustomRNN: h_{t+1} = tanh([x_t | h_t] @ W_ih + b_ih), out = h_final @ W_ho + b_ho
// BATCH=512, SEQ=1024, IN=64, HID=256, CLS=10.
//
// 256 blocks x 512 threads (8 waves, 2/SIMD), one block per CU. Each block
// runs TWO independent 1-row scans (batch rows b0, b0+1), phase-shifted by
// half a step: each phase does {ds_read + 20 MFMA} for one group overlapped
// with {tanh epilogue + h-write + x-stage} for the other, then a raw
// `s_waitcnt lgkmcnt(0); s_barrier`. This fills the MFMA-chain / read-latency
// / TRANS-chain bubbles of one group with the other group's work inside the
// SAME wave (in-order-friendly ILP), instead of relying on wave scheduling.
//
// ROWS=1 per group => every LDS a-frag read is a pure broadcast (4 distinct
// 16B chunks per ds_read_b128) -> zero bank conflicts, no swizzle needed.
// All buffers single-buffered: writer and reader of each LDS panel are always
// separated by a barrier by construction of the phase schedule.
// W_ih (pre-scaled by 2*log2(e), folding tanh's inner multiply) lives in
// registers as 20 bf16 B-fragments per wave (wave w owns cols [32w,32w+32),
// paired col0=32w+2*frow / col0+1 so the epilogue emits one packed b32 write).

#define BATCH 512
#define SEQ   1024
#define INP   64
#define HID   256
#define CLS   10
#define NTHREADS 512
#define NKT   10                   // K-tiles of 32: 2 x-tiles + 8 h-tiles
#define TSCALE 2.8853900817779268f // 2*log2(e)

typedef short bf16x8 __attribute__((ext_vector_type(8)));
typedef float f32x4  __attribute__((ext_vector_type(4)));

static __device__ __forceinline__ unsigned short f2bf(float f) {
  __hip_bfloat16 h = __float2bfloat16(f);   // RNE
  return *reinterpret_cast<unsigned short*>(&h);
}
static __device__ __forceinline__ float bf2f(unsigned short b) {
  union { unsigned int u; float f; } v; v.u = ((unsigned int)b) << 16;
  return v.f;
}
static __device__ __forceinline__ unsigned int cvt_pk_bf16(float lo, float hi) {
  unsigned int r;
  asm("v_cvt_pk_bf16_f32 %0, %1, %2" : "=v"(r) : "v"(lo), "v"(hi));
  return r;
}
static __device__ __forceinline__ float fast_exp2(float x) {
#if __has_builtin(__builtin_amdgcn_exp2f)
  return __builtin_amdgcn_exp2f(x);
#else
  return __exp2f(x);
#endif
}
static __device__ __forceinline__ float fast_rcp(float x) {
#if __has_builtin(__builtin_amdgcn_rcpf)
  return __builtin_amdgcn_rcpf(x);
#else
  return 1.0f / x;
#endif
}
// pre-activation already scaled by 2*log2(e): tanh(x) = 1 - 2/(1 + exp2(s)).
static __device__ __forceinline__ float tanh_scaled(float s) {
  return 1.0f - 2.0f * fast_rcp(1.0f + fast_exp2(s));
}

// Drain LDS ops only; in-flight global x loads (vmcnt) stay in flight.
#define BARRIER() asm volatile("s_waitcnt lgkmcnt(0)\n\ts_barrier" ::: "memory")

// MFMA for group G: read a-frags (broadcast) from sX[G]/sH[G], 20 MFMAs into
// ACC[nt][p] (2 col-tiles x 3 partial chains; depth <= 4 incl. x-tile).
#define MFMA_GRP(G, ACC) do {                                                   \
    const char* xs_ = (const char*)sX[G];                                       \
    const char* hs_ = (const char*)sH[G];                                       \
    bf16x8 ax0 = *(const bf16x8*)(xs_ + g16);                                   \
    bf16x8 ax1 = *(const bf16x8*)(xs_ + 64 + g16);                              \
    bf16x8 a0 = *(const bf16x8*)(hs_ + 0 * 64 + g16);                           \
    bf16x8 a1 = *(const bf16x8*)(hs_ + 1 * 64 + g16);                           \
    bf16x8 a2 = *(const bf16x8*)(hs_ + 2 * 64 + g16);                           \
    bf16x8 a3 = *(const bf16x8*)(hs_ + 3 * 64 + g16);                           \
    bf16x8 a4 = *(const bf16x8*)(hs_ + 4 * 64 + g16);                           \
    bf16x8 a5 = *(const bf16x8*)(hs_ + 5 * 64 + g16);                           \
    bf16x8 a6 = *(const bf16x8*)(hs_ + 6 * 64 + g16);                           \
    bf16x8 a7 = *(const bf16x8*)(hs_ + 7 * 64 + g16);                           \
    ACC[0][0] = f32x4{bias0, bias0, bias0, bias0};                              \
    ACC[0][1] = f32x4{0.f, 0.f, 0.f, 0.f};                                      \
    ACC[0][2] = f32x4{0.f, 0.f, 0.f, 0.f};                                      \
    ACC[1][0] = f32x4{bias1, bias1, bias1, bias1};                              \
    ACC[1][1] = f32x4{0.f, 0.f, 0.f, 0.f};                                      \
    ACC[1][2] = f32x4{0.f, 0.f, 0.f, 0.f};                                      \
    ACC[0][0] = __builtin_amdgcn_mfma_f32_16x16x32_bf16(ax0, bw[0][0], ACC[0][0], 0, 0, 0); \
    ACC[1][0] = __builtin_amdgcn_mfma_f32_16x16x32_bf16(ax0, bw[0][1], ACC[1][0], 0, 0, 0); \
    ACC[0][1] = __builtin_amdgcn_mfma_f32_16x16x32_bf16(ax1, bw[1][0], ACC[0][1], 0, 0, 0); \
    ACC[1][1] = __builtin_amdgcn_mfma_f32_16x16x32_bf16(ax1, bw[1][1], ACC[1][1], 0, 0, 0); \
    ACC[0][2] = __builtin_amdgcn_mfma_f32_16x16x32_bf16(a0, bw[2][0], ACC[0][2], 0, 0, 0); \
    ACC[1][2] = __builtin_amdgcn_mfma_f32_16x16x32_bf16(a0, bw[2][1], ACC[1][2], 0, 0, 0); \
    ACC[0][0] = __builtin_amdgcn_mfma_f32_16x16x32_bf16(a1, bw[3][0], ACC[0][0], 0, 0, 0); \
    ACC[1][0] = __builtin_amdgcn_mfma_f32_16x16x32_bf16(a1, bw[3][1], ACC[1][0], 0, 0, 0); \
    ACC[0][1] = __builtin_amdgcn_mfma_f32_16x16x32_bf16(a2, bw[4][0], ACC[0][1], 0, 0, 0); \
    ACC[1][1] = __builtin_amdgcn_mfma_f32_16x16x32_bf16(a2, bw[4][1], ACC[1][1], 0, 0, 0); \
    ACC[0][2] = __builtin_amdgcn_mfma_f32_16x16x32_bf16(a3, bw[5][0], ACC[0][2], 0, 0, 0); \
    ACC[1][2] = __builtin_amdgcn_mfma_f32_16x16x32_bf16(a3, bw[5][1], ACC[1][2], 0, 0, 0); \
    ACC[0][0] = __builtin_amdgcn_mfma_f32_16x16x32_bf16(a4, bw[6][0], ACC[0][0], 0, 0, 0); \
    ACC[1][0] = __builtin_amdgcn_mfma_f32_16x16x32_bf16(a4, bw[6][1], ACC[1][0], 0, 0, 0); \
    ACC[0][1] = __builtin_amdgcn_mfma_f32_16x16x32_bf16(a5, bw[7][0], ACC[0][1], 0, 0, 0); \
    ACC[1][1] = __builtin_amdgcn_mfma_f32_16x16x32_bf16(a5, bw[7][1], ACC[1][1], 0, 0, 0); \
    ACC[0][2] = __builtin_amdgcn_mfma_f32_16x16x32_bf16(a6, bw[8][0], ACC[0][2], 0, 0, 0); \
    ACC[1][2] = __builtin_amdgcn_mfma_f32_16x16x32_bf16(a6, bw[8][1], ACC[1][2], 0, 0, 0); \
    ACC[0][0] = __builtin_amdgcn_mfma_f32_16x16x32_bf16(a7, bw[9][0], ACC[0][0], 0, 0, 0); \
    ACC[1][0] = __builtin_amdgcn_mfma_f32_16x16x32_bf16(a7, bw[9][1], ACC[1][0], 0, 0, 0); \
  } while (0)

// Epilogue for group G: only D row 0 (g==0, j==0) is a real batch row.
// All lanes compute (cheap); 16 lanes write one packed b32 (cols col0,col0+1).
#define EPI_GRP(G, ACC) do {                                                    \
    float s0_ = ACC[0][0][0] + ACC[0][1][0] + ACC[0][2][0];                     \
    float s1_ = ACC[1][0][0] + ACC[1][1][0] + ACC[1][2][0];                     \
    float t0_ = tanh_scaled(s0_);                                               \
    float t1_ = tanh_scaled(s1_);                                               \
    if (g == 0)                                                                 \
      ((unsigned int*)sH[G])[wave * 16 + frow] = cvt_pk_bf16(t0_, t1_);         \
  } while (0)

// Stage x_G(t) (held in xr, loaded >=1 full step ago) into sX[G]; then issue
// the global load for x_G(TN) into xr. Wave G owns group G's staging.
#define STAGE(G, TN) do {                                                       \
    if (wave == (G) && lane < 32) {                                             \
      ((unsigned int*)sX[G])[lane] = cvt_pk_bf16(xr.x, xr.y);                   \
      int tn_ = (TN); tn_ = tn_ < SEQ ? tn_ : SEQ - 1;                          \
      xr = *(const float2*)&xrow[(size_t)tn_ * INP];                            \
    }                                                                           \
  } while (0)

__global__ __launch_bounds__(NTHREADS, 2)
void rnn_scan_kernel(const float* __restrict__ x,
                     const float* __restrict__ W_ih,
                     const float* __restrict__ b_ih,
                     const float* __restrict__ W_ho,
                     const float* __restrict__ b_ho,
                     float* __restrict__ out) {
  __shared__ __align__(16) unsigned short sH[2][HID];  // h(t) per group, bf16
  __shared__ __align__(16) unsigned short sX[2][INP];  // x(t) per group, bf16

  const int tid  = threadIdx.x;
  const int lane = tid & 63;
  const int wave = tid >> 6;
  const int b0   = blockIdx.x * 2;

  const int g    = (lane >> 4) & 3;   // k-group within fragment
  const int g16  = g * 16;
  const int frow = lane & 15;         // B/D tile-col index
  const int col0 = wave * 32 + 2 * frow;

  // per-thread x source (wave 0 -> group 0 / row b0, wave 1 -> group 1)
  const float* xrow = x + (size_t)(b0 + (wave & 1)) * SEQ * INP + lane * 2;
  float2 xr = make_float2(0.f, 0.f);

  // ---- Preload W_ih as B-fragments (bf16, pre-scaled by TSCALE).
  // B-frag: tile-col = frow (global col col0+nt), k = kt*32 + g*8 + i.
  bf16x8 bw[NKT][2];
  const float bias0 = b_ih[col0] * TSCALE;
  const float bias1 = b_ih[col0 + 1] * TSCALE;
#pragma unroll
  for (int nt = 0; nt < 2; ++nt) {
#pragma unroll
    for (int kt = 0; kt < NKT; ++kt) {
      bf16x8 v;
#pragma unroll
      for (int i = 0; i < 8; ++i)
        v[i] = (short)f2bf(W_ih[(size_t)(kt * 32 + g * 8 + i) * HID + col0 + nt] * TSCALE);
      bw[kt][nt] = v;
    }
  }

  // ---- Prologue: h(0)=0 both groups; stage x0(0); preload xr per role.
  if (tid < 256) ((unsigned int*)sH)[tid] = 0u;   // 2*256 bf16 = 256 dwords
  if (wave == 0 && lane < 32) {
    float2 v0 = *(const float2*)&xrow[0];         // x0(0)
    ((unsigned int*)sX[0])[lane] = cvt_pk_bf16(v0.x, v0.y);
    xr = *(const float2*)&xrow[INP];              // x0(1)
  }
  if (wave == 1 && lane < 32)
    xr = *(const float2*)&xrow[0];                // x1(0)
  BARRIER();

  f32x4 acc0[2][3], acc1[2][3];

  // ---- Peeled PhaseA(0): group0 MFMA(t=0); stage x1(0), load x1(1).
  MFMA_GRP(0, acc0);
  STAGE(1, 1);
  BARRIER();

  // ---- Main loop: iteration i runs PhaseB(i) then PhaseA(i+1).
#pragma unroll 1
  for (int i = 0; i < SEQ - 1; ++i) {
    // PhaseB(i): g1 read+MFMA(t=i) || g0 epilogue->h0(i+1), stage x0(i+1)
    MFMA_GRP(1, acc1);
    EPI_GRP(0, acc0);
    STAGE(0, i + 2);
    BARRIER();
    // PhaseA(i+1): g0 read+MFMA(t=i+1) || g1 epilogue->h1(i+1), stage x1(i+1)
    MFMA_GRP(0, acc0);
    EPI_GRP(1, acc1);
    STAGE(1, i + 2);
    BARRIER();
  }

  // ---- Tail: PhaseB(SEQ-1), then final group1 epilogue.
  MFMA_GRP(1, acc1);
  EPI_GRP(0, acc0);     // h0(SEQ)
  BARRIER();
  EPI_GRP(1, acc1);     // h1(SEQ)
  BARRIER();

  // ---- Head: out[b0+r] = h_r(SEQ) @ W_ho + b_ho  (2 rows x 10 cols)
  if (tid < 2 * CLS) {
    const int r = tid / CLS, cl = tid - r * CLS;
    const unsigned short* hp = sH[r];
    float s = b_ho[cl];
#pragma unroll 8
    for (int k = 0; k < HID; ++k)
      s += bf2f(hp[k]) * W_ho[(size_t)k * CLS + cl];
    out[(size_t)(b0 + r) * CLS + cl] = s;
  }
}

extern "C" void kernel_launch(void* const* d_in, const int* in_sizes, int n_in,
                              void* d_out, int out_size, void* d_ws, size_t ws_size,
                              hipStream_t stream) {
  const float* x    = (const float*)d_in[0];
  const float* W_ih = (const float*)d_in[1];
  const float* b_ih = (const float*)d_in[2];
  const float* W_ho = (const float*)d_in[3];
  const float* b_ho = (const float*)d_in[4];
  float* out = (float*)d_out;

  rnn_scan_kernel<<<BATCH / 2, NTHREADS, 0, stream>>>(x, W_ih, b_ih, W_ho, b_ho, out);
}

// Round 5
// 830.879 us; speedup vs baseline: 1.1565x; 1.1565x over previous
//
#include <hip/hip_runtime.h>
#include <hip/hip_bf16.h>

// CustomRNN: h_{t+1} = tanh([x_t | h_t] @ W_ih + b_ih), out = h_final @ W_ho + b_ho
// BATCH=512, SEQ=1024, IN=64, HID=256, CLS=10.
//
// 512 blocks x 256 threads (4 waves), ONE batch row per block, TWO blocks
// co-resident per CU (VGPR <= 256 via __launch_bounds__(256,2); LDS ~2KB).
// Wall time = SEQ x per-step latency; two independent barrier domains per CU
// drift and fill each other's serial-chain stalls (barrier -> ds_read burst
// -> MFMA chain -> tanh chain -> ds_write), which a single 8-wave block
// cannot (R3: 1657 cyc/step vs ~390 cyc of pipe work).
//
// Wave w owns output cols [64w, 64w+64) as 4 sub-tiles (p,q), col = 64w+32p+
// 2f+q (paired-col: lane f gets adjacent cols -> one packed b32 h-write).
// W_ih (pre-scaled by 2*log2(e)) in registers: 40 bf16x8 B-frags = 160 VGPR.
// h: 2 x 256 bf16 LDS, double-buffered; ROWS=1 makes every a-frag ds_read a
// 4-address broadcast -> conflict-free, no swizzle. x: global->reg, 2 steps
// ahead (unroll-2 static rotation), cvt_pk to bf16 at use; never in LDS.
// Barrier = raw `s_waitcnt lgkmcnt(0); s_barrier` (vmcnt stays in flight).

#define BATCH 512
#define SEQ   1024
#define INP   64
#define HID   256
#define CLS   10
#define NTHREADS 256
#define TSCALE 2.8853900817779268f // 2*log2(e), folded into W_ih/b_ih

typedef short bf16x8 __attribute__((ext_vector_type(8)));
typedef float f32x4  __attribute__((ext_vector_type(4)));
typedef unsigned int u32x4 __attribute__((ext_vector_type(4)));

static __device__ __forceinline__ unsigned short f2bf(float f) {
  __hip_bfloat16 h = __float2bfloat16(f);   // RNE
  return *reinterpret_cast<unsigned short*>(&h);
}
static __device__ __forceinline__ float bf2f(unsigned short b) {
  union { unsigned int u; float f; } v; v.u = ((unsigned int)b) << 16;
  return v.f;
}
static __device__ __forceinline__ unsigned int cvt_pk_bf16(float lo, float hi) {
  unsigned int r;
  asm("v_cvt_pk_bf16_f32 %0, %1, %2" : "=v"(r) : "v"(lo), "v"(hi));
  return r;
}
static __device__ __forceinline__ float fast_exp2(float x) {
#if __has_builtin(__builtin_amdgcn_exp2f)
  return __builtin_amdgcn_exp2f(x);
#else
  return __exp2f(x);
#endif
}
static __device__ __forceinline__ float fast_rcp(float x) {
#if __has_builtin(__builtin_amdgcn_rcpf)
  return __builtin_amdgcn_rcpf(x);
#else
  return 1.0f / x;
#endif
}
// pre-activation already scaled by 2*log2(e): tanh(x) = 1 - 2/(1 + exp2(s)).
static __device__ __forceinline__ float tanh_scaled(float s) {
  return 1.0f - 2.0f * fast_rcp(1.0f + fast_exp2(s));
}
// Build a bf16x8 A-frag from 8 f32 (two f32x4), RNE via v_cvt_pk_bf16_f32.
static __device__ __forceinline__ bf16x8 pack_frag(f32x4 lo, f32x4 hi) {
  u32x4 u;
  u[0] = cvt_pk_bf16(lo[0], lo[1]);
  u[1] = cvt_pk_bf16(lo[2], lo[3]);
  u[2] = cvt_pk_bf16(hi[0], hi[1]);
  u[3] = cvt_pk_bf16(hi[2], hi[3]);
  return __builtin_bit_cast(bf16x8, u);
}

// Drain LDS ops only; in-flight global x loads (vmcnt) stay pending.
#define BARRIER() asm volatile("s_waitcnt lgkmcnt(0)\n\ts_barrier" ::: "memory")

// One scan step. X0..X3: f32x4 regs holding x_T (loaded 2 steps ago); after
// converting to frags they are reloaded with x_{T+2}. CUR: static h-buffer.
#define STEP(T, X0, X1, X2, X3, CUR) do {                                       \
    const char* hs_ = (const char*)sH[CUR];                                     \
    bf16x8 a0 = *(const bf16x8*)(hs_ + 0 * 64 + g16);                           \
    bf16x8 a1 = *(const bf16x8*)(hs_ + 1 * 64 + g16);                           \
    bf16x8 a2 = *(const bf16x8*)(hs_ + 2 * 64 + g16);                           \
    bf16x8 a3 = *(const bf16x8*)(hs_ + 3 * 64 + g16);                           \
    bf16x8 a4 = *(const bf16x8*)(hs_ + 4 * 64 + g16);                           \
    bf16x8 a5 = *(const bf16x8*)(hs_ + 5 * 64 + g16);                           \
    bf16x8 a6 = *(const bf16x8*)(hs_ + 6 * 64 + g16);                           \
    bf16x8 a7 = *(const bf16x8*)(hs_ + 7 * 64 + g16);                           \
    bf16x8 ax0 = pack_frag(X0, X1);                                             \
    bf16x8 ax1 = pack_frag(X2, X3);                                             \
    { int tn_ = (T) + 2; tn_ = tn_ < SEQ ? tn_ : SEQ - 1;                       \
      const float* p_ = xlane + (size_t)tn_ * INP;                              \
      X0 = *(const f32x4*)(p_);      X1 = *(const f32x4*)(p_ + 4);              \
      X2 = *(const f32x4*)(p_ + 32); X3 = *(const f32x4*)(p_ + 36); }           \
    f32x4 acc00 = {bias00, 0.f, 0.f, 0.f};                                      \
    f32x4 acc01 = {bias01, 0.f, 0.f, 0.f};                                      \
    f32x4 acc10 = {bias10, 0.f, 0.f, 0.f};                                      \
    f32x4 acc11 = {bias11, 0.f, 0.f, 0.f};                                      \
    acc00 = __builtin_amdgcn_mfma_f32_16x16x32_bf16(ax0, bw[0][0][0], acc00, 0, 0, 0); \
    acc01 = __builtin_amdgcn_mfma_f32_16x16x32_bf16(ax0, bw[0][0][1], acc01, 0, 0, 0); \
    acc10 = __builtin_amdgcn_mfma_f32_16x16x32_bf16(ax0, bw[0][1][0], acc10, 0, 0, 0); \
    acc11 = __builtin_amdgcn_mfma_f32_16x16x32_bf16(ax0, bw[0][1][1], acc11, 0, 0, 0); \
    acc00 = __builtin_amdgcn_mfma_f32_16x16x32_bf16(ax1, bw[1][0][0], acc00, 0, 0, 0); \
    acc01 = __builtin_amdgcn_mfma_f32_16x16x32_bf16(ax1, bw[1][0][1], acc01, 0, 0, 0); \
    acc10 = __builtin_amdgcn_mfma_f32_16x16x32_bf16(ax1, bw[1][1][0], acc10, 0, 0, 0); \
    acc11 = __builtin_amdgcn_mfma_f32_16x16x32_bf16(ax1, bw[1][1][1], acc11, 0, 0, 0); \
    _Pragma("unroll")                                                           \
    for (int kt = 0; kt < 8; ++kt) {                                            \
      bf16x8 ah_;                                                               \
      switch (kt) { case 0: ah_ = a0; break; case 1: ah_ = a1; break;           \
                    case 2: ah_ = a2; break; case 3: ah_ = a3; break;           \
                    case 4: ah_ = a4; break; case 5: ah_ = a5; break;           \
                    case 6: ah_ = a6; break; default: ah_ = a7; }               \
      acc00 = __builtin_amdgcn_mfma_f32_16x16x32_bf16(ah_, bw[kt + 2][0][0], acc00, 0, 0, 0); \
      acc01 = __builtin_amdgcn_mfma_f32_16x16x32_bf16(ah_, bw[kt + 2][0][1], acc01, 0, 0, 0); \
      acc10 = __builtin_amdgcn_mfma_f32_16x16x32_bf16(ah_, bw[kt + 2][1][0], acc10, 0, 0, 0); \
      acc11 = __builtin_amdgcn_mfma_f32_16x16x32_bf16(ah_, bw[kt + 2][1][1], acc11, 0, 0, 0); \
    }                                                                           \
    /* A-rows are 16 copies of the real row -> D rows identical; use row 0. */ \
    float t00 = tanh_scaled(acc00[0]);                                          \
    float t01 = tanh_scaled(acc01[0]);                                          \
    float t10 = tanh_scaled(acc10[0]);                                          \
    float t11 = tanh_scaled(acc11[0]);                                          \
    if (g == 0) {                                                               \
      unsigned int* hd_ = (unsigned int*)sH[(CUR) ^ 1];                         \
      hd_[32 * wave + frow]      = cvt_pk_bf16(t00, t01);                       \
      hd_[32 * wave + 16 + frow] = cvt_pk_bf16(t10, t11);                       \
    }                                                                           \
    BARRIER();                                                                  \
  } while (0)

__global__ __launch_bounds__(NTHREADS, 2)
void rnn_scan_kernel(const float* __restrict__ x,
                     const float* __restrict__ W_ih,
                     const float* __restrict__ b_ih,
                     const float* __restrict__ W_ho,
                     const float* __restrict__ b_ho,
                     float* __restrict__ out) {
  __shared__ __align__(16) unsigned short sH[2][HID];  // h(t), h(t+1): 2x512B

  const int tid  = threadIdx.x;
  const int lane = tid & 63;
  const int wave = tid >> 6;          // 0..3
  const int row  = blockIdx.x;        // one batch row per block

  const int g    = (lane >> 4) & 3;   // k-group within fragment
  const int g16  = g * 16;
  const int frow = lane & 15;         // B/D tile-col index

  // ---- Preload W_ih as B-fragments (bf16, pre-scaled by TSCALE).
  // Sub-tile (p,q): global col = 64*wave + 32p + 2*frow + q.
  // B-frag: lane (g,frow) holds B[k = kt*32 + g*8 + i][tile-col frow].
  bf16x8 bw[10][2][2];
  float bias00, bias01, bias10, bias11;
#pragma unroll
  for (int p = 0; p < 2; ++p) {
#pragma unroll
    for (int q = 0; q < 2; ++q) {
      const int col = 64 * wave + 32 * p + 2 * frow + q;
      const float bb = b_ih[col] * TSCALE;
      if (p == 0 && q == 0) bias00 = bb;
      if (p == 0 && q == 1) bias01 = bb;
      if (p == 1 && q == 0) bias10 = bb;
      if (p == 1 && q == 1) bias11 = bb;
#pragma unroll
      for (int kt = 0; kt < 10; ++kt) {
        bf16x8 v;
#pragma unroll
        for (int i = 0; i < 8; ++i)
          v[i] = (short)f2bf(W_ih[(size_t)(kt * 32 + g * 8 + i) * HID + col] * TSCALE);
        bw[kt][p][q] = v;
      }
    }
  }

  // ---- x source: lane (g,*) needs x[t*64 + g*8 .. +8) and x[t*64+32+g*8 ..).
  const float* xlane = x + (size_t)row * SEQ * INP + g * 8;
  f32x4 xe0 = *(const f32x4*)(xlane + 0);            // t = 0
  f32x4 xe1 = *(const f32x4*)(xlane + 4);
  f32x4 xe2 = *(const f32x4*)(xlane + 32);
  f32x4 xe3 = *(const f32x4*)(xlane + 36);
  f32x4 xo0 = *(const f32x4*)(xlane + INP + 0);      // t = 1
  f32x4 xo1 = *(const f32x4*)(xlane + INP + 4);
  f32x4 xo2 = *(const f32x4*)(xlane + INP + 32);
  f32x4 xo3 = *(const f32x4*)(xlane + INP + 36);

  // ---- h(0) = 0 in buffer 0
  if (tid < HID / 2) ((unsigned int*)sH[0])[tid] = 0u;
  BARRIER();

  // ---- Main scan: unroll-2 -> static x-register rotation + buffer flip
#pragma unroll 1
  for (int t = 0; t < SEQ; t += 2) {
    STEP(t,     xe0, xe1, xe2, xe3, 0);
    STEP(t + 1, xo0, xo1, xo2, xo3, 1);
  }
  // SEQ even -> h_final in sH[0]

  // ---- Head: out[row] = h_final @ W_ho + b_ho (10 cols, once per block)
  if (tid < CLS) {
    const int cl = tid;
    float s = b_ho[cl];
#pragma unroll 8
    for (int k = 0; k < HID; ++k)
      s += bf2f(sH[0][k]) * W_ho[(size_t)k * CLS + cl];
    out[(size_t)row * CLS + cl] = s;
  }
}

extern "C" void kernel_launch(void* const* d_in, const int* in_sizes, int n_in,
                              void* d_out, int out_size, void* d_ws, size_t ws_size,
                              hipStream_t stream) {
  const float* x    = (const float*)d_in[0];
  const float* W_ih = (const float*)d_in[1];
  const float* b_ih = (const float*)d_in[2];
  const float* W_ho = (const float*)d_in[3];
  const float* b_ho = (const float*)d_in[4];
  float* out = (float*)d_out;

  rnn_scan_kernel<<<BATCH, NTHREADS, 0, stream>>>(x, W_ih, b_ih, W_ho, b_ho, out);
}

// Round 6
// 788.026 us; speedup vs baseline: 1.2194x; 1.0544x over previous
//
#include <hip/hip_runtime.h>
#include <hip/hip_bf16.h>

// CustomRNN: h_{t+1} = tanh([x_t | h_t] @ W_ih + b_ih), out = h_final @ W_ho + b_ho
// BATCH=512, SEQ=1024, IN=64, HID=256, CLS=10.
//
// 512 blocks x 256 threads (4 waves), ONE batch row per block, TWO blocks
// co-resident per CU -> two independent barrier domains drift and fill each
// other's serial-chain stalls. R5 proved the structure (MfmaUtil 64%) but
// spilled: ~270 VGPR demand vs the allocator's chosen 128. This version:
//   (a) amdgpu_waves_per_eu(2,2) pins the budget to 256 regs/wave,
//   (b) x goes through a tiny LDS panel again (stage by wave 0, 2-step-deep
//       float2 prefetch) instead of 32 f32 registers per lane,
// bringing demand to ~245 < 256. Weights stay fully register-resident:
// wave w owns cols [64w,64w+64) as 4 sub-tiles -> 40 bf16x8 B-frags = 160 VGPR.
// h: 2x256 bf16 LDS double-buffered; 1-row blocks make every a-frag ds_read a
// broadcast (conflict-free, no swizzle). Barrier = raw lgkmcnt(0)+s_barrier
// (in-flight global x loads never drained).

#define BATCH 512
#define SEQ   1024
#define INP   64
#define HID   256
#define CLS   10
#define NTHREADS 256
#define TSCALE 2.8853900817779268f // 2*log2(e), folded into W_ih/b_ih

typedef short bf16x8 __attribute__((ext_vector_type(8)));
typedef float f32x4  __attribute__((ext_vector_type(4)));

static __device__ __forceinline__ unsigned short f2bf(float f) {
  __hip_bfloat16 h = __float2bfloat16(f);   // RNE
  return *reinterpret_cast<unsigned short*>(&h);
}
static __device__ __forceinline__ float bf2f(unsigned short b) {
  union { unsigned int u; float f; } v; v.u = ((unsigned int)b) << 16;
  return v.f;
}
static __device__ __forceinline__ unsigned int cvt_pk_bf16(float lo, float hi) {
  unsigned int r;
  asm("v_cvt_pk_bf16_f32 %0, %1, %2" : "=v"(r) : "v"(lo), "v"(hi));
  return r;
}
static __device__ __forceinline__ float fast_exp2(float x) {
#if __has_builtin(__builtin_amdgcn_exp2f)
  return __builtin_amdgcn_exp2f(x);
#else
  return __exp2f(x);
#endif
}
static __device__ __forceinline__ float fast_rcp(float x) {
#if __has_builtin(__builtin_amdgcn_rcpf)
  return __builtin_amdgcn_rcpf(x);
#else
  return 1.0f / x;
#endif
}
// pre-activation already scaled by 2*log2(e): tanh(x) = 1 - 2/(1 + exp2(s)).
static __device__ __forceinline__ float tanh_scaled(float s) {
  return 1.0f - 2.0f * fast_rcp(1.0f + fast_exp2(s));
}

// Drain LDS ops only; in-flight global x loads (vmcnt) stay pending.
#define BARRIER() asm volatile("s_waitcnt lgkmcnt(0)\n\ts_barrier" ::: "memory")

// One scan step. Reads h(T) from sH[CUR] and x(T) from sX[CUR] (broadcast
// ds_reads), stages x(T+1) (in XR, loaded 2 steps ago) into sX[CUR^1] and
// reloads XR with x(T+3), does 40 MFMAs, tanh epilogue into sH[CUR^1].
#define STEP(T, CUR, XR) do {                                                   \
    const char* hs_ = (const char*)sH[CUR];                                     \
    const char* xs_ = (const char*)sX[CUR];                                     \
    bf16x8 ax0 = *(const bf16x8*)(xs_ + g16);                                   \
    bf16x8 ax1 = *(const bf16x8*)(xs_ + 64 + g16);                              \
    bf16x8 a0 = *(const bf16x8*)(hs_ + 0 * 64 + g16);                           \
    bf16x8 a1 = *(const bf16x8*)(hs_ + 1 * 64 + g16);                           \
    bf16x8 a2 = *(const bf16x8*)(hs_ + 2 * 64 + g16);                           \
    bf16x8 a3 = *(const bf16x8*)(hs_ + 3 * 64 + g16);                           \
    bf16x8 a4 = *(const bf16x8*)(hs_ + 4 * 64 + g16);                           \
    bf16x8 a5 = *(const bf16x8*)(hs_ + 5 * 64 + g16);                           \
    bf16x8 a6 = *(const bf16x8*)(hs_ + 6 * 64 + g16);                           \
    bf16x8 a7 = *(const bf16x8*)(hs_ + 7 * 64 + g16);                           \
    if (wave == 0 && lane < 32) {                                               \
      ((unsigned int*)sX[(CUR) ^ 1])[lane] = cvt_pk_bf16(XR.x, XR.y);           \
      int tn_ = (T) + 3; tn_ = tn_ < SEQ ? tn_ : SEQ - 1;                       \
      XR = *(const float2*)&xstage[(size_t)tn_ * INP];                          \
    }                                                                           \
    f32x4 acc00 = {bias00, 0.f, 0.f, 0.f};                                      \
    f32x4 acc01 = {bias01, 0.f, 0.f, 0.f};                                      \
    f32x4 acc10 = {bias10, 0.f, 0.f, 0.f};                                      \
    f32x4 acc11 = {bias11, 0.f, 0.f, 0.f};                                      \
    acc00 = __builtin_amdgcn_mfma_f32_16x16x32_bf16(ax0, bw[0][0][0], acc00, 0, 0, 0); \
    acc01 = __builtin_amdgcn_mfma_f32_16x16x32_bf16(ax0, bw[0][0][1], acc01, 0, 0, 0); \
    acc10 = __builtin_amdgcn_mfma_f32_16x16x32_bf16(ax0, bw[0][1][0], acc10, 0, 0, 0); \
    acc11 = __builtin_amdgcn_mfma_f32_16x16x32_bf16(ax0, bw[0][1][1], acc11, 0, 0, 0); \
    acc00 = __builtin_amdgcn_mfma_f32_16x16x32_bf16(ax1, bw[1][0][0], acc00, 0, 0, 0); \
    acc01 = __builtin_amdgcn_mfma_f32_16x16x32_bf16(ax1, bw[1][0][1], acc01, 0, 0, 0); \
    acc10 = __builtin_amdgcn_mfma_f32_16x16x32_bf16(ax1, bw[1][1][0], acc10, 0, 0, 0); \
    acc11 = __builtin_amdgcn_mfma_f32_16x16x32_bf16(ax1, bw[1][1][1], acc11, 0, 0, 0); \
    acc00 = __builtin_amdgcn_mfma_f32_16x16x32_bf16(a0, bw[2][0][0], acc00, 0, 0, 0); \
    acc01 = __builtin_amdgcn_mfma_f32_16x16x32_bf16(a0, bw[2][0][1], acc01, 0, 0, 0); \
    acc10 = __builtin_amdgcn_mfma_f32_16x16x32_bf16(a0, bw[2][1][0], acc10, 0, 0, 0); \
    acc11 = __builtin_amdgcn_mfma_f32_16x16x32_bf16(a0, bw[2][1][1], acc11, 0, 0, 0); \
    acc00 = __builtin_amdgcn_mfma_f32_16x16x32_bf16(a1, bw[3][0][0], acc00, 0, 0, 0); \
    acc01 = __builtin_amdgcn_mfma_f32_16x16x32_bf16(a1, bw[3][0][1], acc01, 0, 0, 0); \
    acc10 = __builtin_amdgcn_mfma_f32_16x16x32_bf16(a1, bw[3][1][0], acc10, 0, 0, 0); \
    acc11 = __builtin_amdgcn_mfma_f32_16x16x32_bf16(a1, bw[3][1][1], acc11, 0, 0, 0); \
    acc00 = __builtin_amdgcn_mfma_f32_16x16x32_bf16(a2, bw[4][0][0], acc00, 0, 0, 0); \
    acc01 = __builtin_amdgcn_mfma_f32_16x16x32_bf16(a2, bw[4][0][1], acc01, 0, 0, 0); \
    acc10 = __builtin_amdgcn_mfma_f32_16x16x32_bf16(a2, bw[4][1][0], acc10, 0, 0, 0); \
    acc11 = __builtin_amdgcn_mfma_f32_16x16x32_bf16(a2, bw[4][1][1], acc11, 0, 0, 0); \
    acc00 = __builtin_amdgcn_mfma_f32_16x16x32_bf16(a3, bw[5][0][0], acc00, 0, 0, 0); \
    acc01 = __builtin_amdgcn_mfma_f32_16x16x32_bf16(a3, bw[5][0][1], acc01, 0, 0, 0); \
    acc10 = __builtin_amdgcn_mfma_f32_16x16x32_bf16(a3, bw[5][1][0], acc10, 0, 0, 0); \
    acc11 = __builtin_amdgcn_mfma_f32_16x16x32_bf16(a3, bw[5][1][1], acc11, 0, 0, 0); \
    acc00 = __builtin_amdgcn_mfma_f32_16x16x32_bf16(a4, bw[6][0][0], acc00, 0, 0, 0); \
    acc01 = __builtin_amdgcn_mfma_f32_16x16x32_bf16(a4, bw[6][0][1], acc01, 0, 0, 0); \
    acc10 = __builtin_amdgcn_mfma_f32_16x16x32_bf16(a4, bw[6][1][0], acc10, 0, 0, 0); \
    acc11 = __builtin_amdgcn_mfma_f32_16x16x32_bf16(a4, bw[6][1][1], acc11, 0, 0, 0); \
    acc00 = __builtin_amdgcn_mfma_f32_16x16x32_bf16(a5, bw[7][0][0], acc00, 0, 0, 0); \
    acc01 = __builtin_amdgcn_mfma_f32_16x16x32_bf16(a5, bw[7][0][1], acc01, 0, 0, 0); \
    acc10 = __builtin_amdgcn_mfma_f32_16x16x32_bf16(a5, bw[7][1][0], acc10, 0, 0, 0); \
    acc11 = __builtin_amdgcn_mfma_f32_16x16x32_bf16(a5, bw[7][1][1], acc11, 0, 0, 0); \
    acc00 = __builtin_amdgcn_mfma_f32_16x16x32_bf16(a6, bw[8][0][0], acc00, 0, 0, 0); \
    acc01 = __builtin_amdgcn_mfma_f32_16x16x32_bf16(a6, bw[8][0][1], acc01, 0, 0, 0); \
    acc10 = __builtin_amdgcn_mfma_f32_16x16x32_bf16(a6, bw[8][1][0], acc10, 0, 0, 0); \
    acc11 = __builtin_amdgcn_mfma_f32_16x16x32_bf16(a6, bw[8][1][1], acc11, 0, 0, 0); \
    acc00 = __builtin_amdgcn_mfma_f32_16x16x32_bf16(a7, bw[9][0][0], acc00, 0, 0, 0); \
    acc01 = __builtin_amdgcn_mfma_f32_16x16x32_bf16(a7, bw[9][0][1], acc01, 0, 0, 0); \
    acc10 = __builtin_amdgcn_mfma_f32_16x16x32_bf16(a7, bw[9][1][0], acc10, 0, 0, 0); \
    acc11 = __builtin_amdgcn_mfma_f32_16x16x32_bf16(a7, bw[9][1][1], acc11, 0, 0, 0); \
    /* A-rows are 16 copies of the real row -> D rows identical; use j=0,   */ \
    /* which is batch-row 0 on g==0 lanes. */                                  \
    float t00 = tanh_scaled(acc00[0]);                                          \
    float t01 = tanh_scaled(acc01[0]);                                          \
    float t10 = tanh_scaled(acc10[0]);                                          \
    float t11 = tanh_scaled(acc11[0]);                                          \
    if (g == 0) {                                                               \
      unsigned int* hd_ = (unsigned int*)sH[(CUR) ^ 1];                         \
      hd_[32 * wave + frow]      = cvt_pk_bf16(t00, t01);                       \
      hd_[32 * wave + 16 + frow] = cvt_pk_bf16(t10, t11);                       \
    }                                                                           \
    BARRIER();                                                                  \
  } while (0)

__global__ __launch_bounds__(NTHREADS)
__attribute__((amdgpu_waves_per_eu(2, 2)))
void rnn_scan_kernel(const float* __restrict__ x,
                     const float* __restrict__ W_ih,
                     const float* __restrict__ b_ih,
                     const float* __restrict__ W_ho,
                     const float* __restrict__ b_ho,
                     float* __restrict__ out) {
  __shared__ __align__(16) unsigned short sH[2][HID];  // h(t)/h(t+1): 2x512B
  __shared__ __align__(16) unsigned short sX[2][INP];  // x(t)/x(t+1): 2x128B

  const int tid  = threadIdx.x;
  const int lane = tid & 63;
  const int wave = tid >> 6;          // 0..3
  const int row  = blockIdx.x;        // one batch row per block

  const int g    = (lane >> 4) & 3;   // k-group within fragment
  const int g16  = g * 16;
  const int frow = lane & 15;         // B/D tile-col index

  // ---- Preload W_ih as B-fragments (bf16, pre-scaled by TSCALE).
  // Sub-tile (p,q): global col = 64*wave + 32p + 2*frow + q.
  // B-frag: lane (g,frow) holds B[k = kt*32 + g*8 + i][tile-col frow].
  bf16x8 bw[10][2][2];
  float bias00, bias01, bias10, bias11;
#pragma unroll
  for (int p = 0; p < 2; ++p) {
#pragma unroll
    for (int q = 0; q < 2; ++q) {
      const int col = 64 * wave + 32 * p + 2 * frow + q;
      const float bb = b_ih[col] * TSCALE;
      if (p == 0 && q == 0) bias00 = bb;
      if (p == 0 && q == 1) bias01 = bb;
      if (p == 1 && q == 0) bias10 = bb;
      if (p == 1 && q == 1) bias11 = bb;
#pragma unroll
      for (int kt = 0; kt < 10; ++kt) {
        bf16x8 v;
#pragma unroll
        for (int i = 0; i < 8; ++i)
          v[i] = (short)f2bf(W_ih[(size_t)(kt * 32 + g * 8 + i) * HID + col] * TSCALE);
        bw[kt][p][q] = v;
      }
    }
  }

  // ---- x staging source: wave 0, lanes 0..31, 2 floats per lane.
  const float* xstage = x + (size_t)row * SEQ * INP + lane * 2;
  float2 xrA = make_float2(0.f, 0.f), xrB = make_float2(0.f, 0.f);

  // ---- Prologue: h(0)=0; stage x(0) into sX[0]; preload xrA=x(1), xrB=x(2).
  if (tid < HID / 2) ((unsigned int*)sH[0])[tid] = 0u;
  if (wave == 0 && lane < 32) {
    float2 v0 = *(const float2*)&xstage[0];
    ((unsigned int*)sX[0])[lane] = cvt_pk_bf16(v0.x, v0.y);
    xrA = *(const float2*)&xstage[(size_t)1 * INP];
    xrB = *(const float2*)&xstage[(size_t)2 * INP];
  }
  BARRIER();

  // ---- Main scan: unroll-2 -> static buffer flip + x-register rotation.
#pragma unroll 1
  for (int t = 0; t < SEQ; t += 2) {
    STEP(t,     0, xrA);
    STEP(t + 1, 1, xrB);
  }
  // SEQ even -> h_final in sH[0]

  // ---- Head: out[row] = h_final @ W_ho + b_ho (10 cols, once per block)
  if (tid < CLS) {
    const int cl = tid;
    float s = b_ho[cl];
#pragma unroll 4
    for (int kb = 0; kb < HID / 8; ++kb) {
      bf16x8 hv = *(const bf16x8*)&sH[0][kb * 8];
#pragma unroll
      for (int i = 0; i < 8; ++i)
        s += bf2f((unsigned short)hv[i]) * W_ho[(size_t)(kb * 8 + i) * CLS + cl];
    }
    out[(size_t)row * CLS + cl] = s;
  }
}

extern "C" void kernel_launch(void* const* d_in, const int* in_sizes, int n_in,
                              void* d_out, int out_size, void* d_ws, size_t ws_size,
                              hipStream_t stream) {
  const float* x    = (const float*)d_in[0];
  const float* W_ih = (const float*)d_in[1];
  const float* b_ih = (const float*)d_in[2];
  const float* W_ho = (const float*)d_in[3];
  const float* b_ho = (const float*)d_in[4];
  float* out = (float*)d_out;

  rnn_scan_kernel<<<BATCH, NTHREADS, 0, stream>>>(x, W_ih, b_ih, W_ho, b_ho, out);
}

// Round 7
// 547.681 us; speedup vs baseline: 1.7545x; 1.4388x over previous
//
#include <hip/hip_runtime.h>
#include <hip/hip_bf16.h>

// CustomRNN: h_{t+1} = tanh([x_t | h_t] @ W_ih + b_ih), out = h_final @ W_ho + b_ho
// BATCH=512, SEQ=1024, IN=64, HID=256, CLS=10.
//
// 256 blocks x 512 threads (8 waves), TWO batch rows per block, 1 block/CU
// (all CUs busy). Cost model from R3/R6: LDS A-frag delivery (~12 cyc per
// ds_read_b128/CU) dominates; each MFMA ingests 1KB of A but only rows 0-1
// are real. So A-reads are EXEC-MASKED to frow<2 (8/64 lanes); masked lanes
// keep stale registers, harmless since D rows 2-15 are discarded.
// Wave w owns cols [32w,32w+32) as 2 paired tiles (col = 32w+2f+q);
// W_ih (pre-scaled by 2*log2(e)) in registers: 20 bf16x8 B-frags = 80 VGPR.
// 1 block/CU -> no 128-reg tier fight: launch_bounds(512,2) caps at 256,
// demand ~130, no spill (R5/R6's failure). h: 2x(2x256) bf16 double-buffered;
// 2-way f0/f1 bank aliasing is free (m136) -> no swizzle, zero conflicts.
// x: 2x(2x64) bf16 panel staged by wave 0 with 2-step reg prefetch.
// Barrier: raw `s_waitcnt lgkmcnt(0); s_barrier` (global x loads stay in
// flight). A-frags prefetched pairwise with sched_barrier(0) fences to cap
// register liveness (~4 frags live).

#define BATCH 512
#define SEQ   1024
#define INP   64
#define HID   256
#define CLS   10
#define NTHREADS 512
#define TSCALE 2.8853900817779268f // 2*log2(e), folded into W_ih/b_ih

typedef short bf16x8 __attribute__((ext_vector_type(8)));
typedef float f32x4  __attribute__((ext_vector_type(4)));

static __device__ __forceinline__ unsigned short f2bf(float f) {
  __hip_bfloat16 h = __float2bfloat16(f);   // RNE
  return *reinterpret_cast<unsigned short*>(&h);
}
static __device__ __forceinline__ float bf2f(unsigned short b) {
  union { unsigned int u; float f; } v; v.u = ((unsigned int)b) << 16;
  return v.f;
}
static __device__ __forceinline__ unsigned int cvt_pk_bf16(float lo, float hi) {
  unsigned int r;
  asm("v_cvt_pk_bf16_f32 %0, %1, %2" : "=v"(r) : "v"(lo), "v"(hi));
  return r;
}
static __device__ __forceinline__ float fast_exp2(float x) {
#if __has_builtin(__builtin_amdgcn_exp2f)
  return __builtin_amdgcn_exp2f(x);
#else
  return __exp2f(x);
#endif
}
static __device__ __forceinline__ float fast_rcp(float x) {
#if __has_builtin(__builtin_amdgcn_rcpf)
  return __builtin_amdgcn_rcpf(x);
#else
  return 1.0f / x;
#endif
}
// pre-activation already scaled by 2*log2(e): tanh(x) = 1 - 2/(1 + exp2(s)).
static __device__ __forceinline__ float tanh_scaled(float s) {
  return 1.0f - 2.0f * fast_rcp(1.0f + fast_exp2(s));
}

#define MFMA16(A, B, C) __builtin_amdgcn_mfma_f32_16x16x32_bf16(A, B, C, 0, 0, 0)

// Drain LDS ops only; in-flight global x loads (vmcnt) stay pending.
#define BARRIER() asm volatile("s_waitcnt lgkmcnt(0)\n\ts_barrier" ::: "memory")

// One scan step (reads buf CUR, writes buf CUR^1, one barrier).
// aP0,aP1,aQ0,aQ1 are persistent frag registers (masked lanes keep old data).
#define STEP(T, CUR, XR) do {                                                   \
    /* stage x(T+1) (in XR, loaded 2 steps ago) -> sX[CUR^1]; XR = x(T+3) */    \
    if (wave == 0) {                                                            \
      ((unsigned int*)sX[(CUR) ^ 1])[lane] = cvt_pk_bf16(XR.x, XR.y);           \
      int tn_ = (T) + 3; tn_ = tn_ < SEQ ? tn_ : SEQ - 1;                       \
      XR = *(const float2*)&xstage[(size_t)tn_ * INP];                          \
    }                                                                           \
    f32x4 acc0 = {bias0, bias0, bias0, bias0};                                  \
    f32x4 acc1 = {bias1, bias1, bias1, bias1};                                  \
    /* masked A-reads: only lanes frow<2 carry real rows */                     \
    if (frow < 2) {                                                             \
      aP0 = *(const bf16x8*)&sX[CUR][frow][g8];                                 \
      aP1 = *(const bf16x8*)&sX[CUR][frow][32 + g8];                            \
      aQ0 = *(const bf16x8*)&sH[CUR][frow][0 * 32 + g8];                        \
      aQ1 = *(const bf16x8*)&sH[CUR][frow][1 * 32 + g8];                        \
    }                                                                           \
    acc0 = MFMA16(aP0, bw[0][0], acc0); acc1 = MFMA16(aP0, bw[0][1], acc1);     \
    acc0 = MFMA16(aP1, bw[1][0], acc0); acc1 = MFMA16(aP1, bw[1][1], acc1);     \
    __builtin_amdgcn_sched_barrier(0);                                          \
    if (frow < 2) {                                                             \
      aP0 = *(const bf16x8*)&sH[CUR][frow][2 * 32 + g8];                        \
      aP1 = *(const bf16x8*)&sH[CUR][frow][3 * 32 + g8];                        \
    }                                                                           \
    acc0 = MFMA16(aQ0, bw[2][0], acc0); acc1 = MFMA16(aQ0, bw[2][1], acc1);     \
    acc0 = MFMA16(aQ1, bw[3][0], acc0); acc1 = MFMA16(aQ1, bw[3][1], acc1);     \
    __builtin_amdgcn_sched_barrier(0);                                          \
    if (frow < 2) {                                                             \
      aQ0 = *(const bf16x8*)&sH[CUR][frow][4 * 32 + g8];                        \
      aQ1 = *(const bf16x8*)&sH[CUR][frow][5 * 32 + g8];                        \
    }                                                                           \
    acc0 = MFMA16(aP0, bw[4][0], acc0); acc1 = MFMA16(aP0, bw[4][1], acc1);     \
    acc0 = MFMA16(aP1, bw[5][0], acc0); acc1 = MFMA16(aP1, bw[5][1], acc1);     \
    __builtin_amdgcn_sched_barrier(0);                                          \
    if (frow < 2) {                                                             \
      aP0 = *(const bf16x8*)&sH[CUR][frow][6 * 32 + g8];                        \
      aP1 = *(const bf16x8*)&sH[CUR][frow][7 * 32 + g8];                        \
    }                                                                           \
    acc0 = MFMA16(aQ0, bw[6][0], acc0); acc1 = MFMA16(aQ0, bw[6][1], acc1);     \
    acc0 = MFMA16(aQ1, bw[7][0], acc0); acc1 = MFMA16(aQ1, bw[7][1], acc1);     \
    __builtin_amdgcn_sched_barrier(0);                                          \
    acc0 = MFMA16(aP0, bw[8][0], acc0); acc1 = MFMA16(aP0, bw[8][1], acc1);     \
    acc0 = MFMA16(aP1, bw[9][0], acc0); acc1 = MFMA16(aP1, bw[9][1], acc1);     \
    /* D: col=lane&15, row=4g+j -> rows 0,1 live in g==0 lanes, j=0,1 */        \
    float t00 = tanh_scaled(acc0[0]);   /* row0, col 32w+2f   */                \
    float t10 = tanh_scaled(acc1[0]);   /* row0, col 32w+2f+1 */                \
    float t01 = tanh_scaled(acc0[1]);   /* row1, col 32w+2f   */                \
    float t11 = tanh_scaled(acc1[1]);   /* row1, col 32w+2f+1 */                \
    if (g == 0) {                                                               \
      unsigned int* hd_ = (unsigned int*)sH[(CUR) ^ 1];                         \
      hd_[0 * 128 + 16 * wave + frow] = cvt_pk_bf16(t00, t10);                  \
      hd_[1 * 128 + 16 * wave + frow] = cvt_pk_bf16(t01, t11);                  \
    }                                                                           \
    BARRIER();                                                                  \
  } while (0)

__global__ __launch_bounds__(NTHREADS, 2)
void rnn_scan_kernel(const float* __restrict__ x,
                     const float* __restrict__ W_ih,
                     const float* __restrict__ b_ih,
                     const float* __restrict__ W_ho,
                     const float* __restrict__ b_ho,
                     float* __restrict__ out) {
  __shared__ __align__(16) unsigned short sH[2][2][HID];  // buf x row x col
  __shared__ __align__(16) unsigned short sX[2][2][INP];

  const int tid  = threadIdx.x;
  const int lane = tid & 63;
  const int wave = tid >> 6;          // 0..7
  const int b0   = blockIdx.x * 2;    // two batch rows per block

  const int g    = (lane >> 4) & 3;   // k-group within fragment
  const int g8   = g * 8;             // element offset within k-tile
  const int frow = lane & 15;         // A-row (reads) / B,D tile-col

  // ---- Preload W_ih as B-fragments (bf16, pre-scaled by TSCALE).
  // Tile q in {0,1}: global col = 32*wave + 2*frow + q (paired cols so the
  // epilogue packs one u32). B-frag: lane (g,f) holds B[kt*32+g*8+i][f].
  bf16x8 bw[10][2];
  const int colE = 32 * wave + 2 * frow;
  const float bias0 = b_ih[colE] * TSCALE;
  const float bias1 = b_ih[colE + 1] * TSCALE;
#pragma unroll
  for (int q = 0; q < 2; ++q) {
#pragma unroll
    for (int kt = 0; kt < 10; ++kt) {
      bf16x8 v;
#pragma unroll
      for (int i = 0; i < 8; ++i)
        v[i] = (short)f2bf(W_ih[(size_t)(kt * 32 + g * 8 + i) * HID + colE + q] * TSCALE);
      bw[kt][q] = v;
    }
  }

  // ---- x staging: wave 0, all 64 lanes. lane -> (row = lane>>5, colpair).
  const int xrow = lane >> 5, xcp = lane & 31;
  const float* xstage = x + (size_t)(b0 + xrow) * SEQ * INP + xcp * 2;
  float2 xrA = make_float2(0.f, 0.f), xrB = make_float2(0.f, 0.f);

  // ---- Persistent A-frag registers (masked lanes keep stale copies).
  bf16x8 aP0 = {}, aP1 = {}, aQ0 = {}, aQ1 = {};

  // ---- Prologue: h(0)=0; stage x(0) -> sX[0]; xrA=x(1), xrB=x(2).
  if (tid < 256) ((unsigned int*)sH[0])[tid] = 0u;
  if (wave == 0) {
    float2 v0 = *(const float2*)&xstage[0];
    ((unsigned int*)sX[0])[lane] = cvt_pk_bf16(v0.x, v0.y);
    xrA = *(const float2*)&xstage[(size_t)1 * INP];
    xrB = *(const float2*)&xstage[(size_t)2 * INP];
  }
  BARRIER();

  // ---- Main scan: unroll-2 -> static buffer flip + x-register rotation.
#pragma unroll 1
  for (int t = 0; t < SEQ; t += 2) {
    STEP(t,     0, xrA);
    STEP(t + 1, 1, xrB);
  }
  // SEQ even -> h_final in sH[0]

  // ---- Head: out[b0+r] = h_final @ W_ho + b_ho (2 rows x 10 cols).
  if (tid < 2 * CLS) {
    const int r = tid / CLS, cl = tid - r * CLS;
    float s = b_ho[cl];
#pragma unroll 8
    for (int k = 0; k < HID; ++k)
      s += bf2f(sH[0][r][k]) * W_ho[(size_t)k * CLS + cl];
    out[(size_t)(b0 + r) * CLS + cl] = s;
  }
}

extern "C" void kernel_launch(void* const* d_in, const int* in_sizes, int n_in,
                              void* d_out, int out_size, void* d_ws, size_t ws_size,
                              hipStream_t stream) {
  const float* x    = (const float*)d_in[0];
  const float* W_ih = (const float*)d_in[1];
  const float* b_ih = (const float*)d_in[2];
  const float* W_ho = (const float*)d_in[3];
  const float* b_ho = (const float*)d_in[4];
  float* out = (float*)d_out;

  rnn_scan_kernel<<<BATCH / 2, NTHREADS, 0, stream>>>(x, W_ih, b_ih, W_ho, b_ho, out);
}

// Round 8
// 529.293 us; speedup vs baseline: 1.8155x; 1.0347x over previous
//
#include <hip/hip_runtime.h>
#include <hip/hip_bf16.h>

// CustomRNN: h_{t+1} = tanh([x_t | h_t] @ W_ih + b_ih), out = h_final @ W_ho + b_ho
// BATCH=512, SEQ=1024, IN=64, HID=256, CLS=10.
//
// 256 blocks x 512 threads (8 waves), TWO batch rows per block, 1 block/CU.
// Wave w owns cols [32w,32w+32) paired (col = 32w+2f+q); W_ih (pre-scaled by
// 2*log2(e)) register-resident: 20 bf16x8 B-frags = 80 VGPR.
// A-reads exec-masked to frow<2 (only rows 0,1 of the M=16 tile are real).
//
// R8 changes vs R7 (each from the counter post-mortem):
//  1. INTERLEAVED LDS layout [kt][row][g-chunk]: element (r,c) lives at byte
//     (c>>5)*128 + r*64 + (c&31)*2. The 8 active lanes of a masked A-read
//     (g=0..3, f=0..1) hit kt*128 + f*64 + 16g -> all 32 banks exactly once.
//     R7's [row][col] layout (512B row stride) made every read a 2-way
//     conflict (SQ_LDS_BANK_CONFLICT = 3.2 cyc/read).
//  2. Accumulator chains split (even/odd kt): dependent-MFMA depth 10 -> 5.
//  3. s_setprio(1) around the MFMA cluster.
// h: 2 x 1KB double-buffered; x: 2 x 256B, staged by wave 0 with a 2-step
// register prefetch. Barrier: raw `s_waitcnt lgkmcnt(0); s_barrier` (global
// x loads stay in flight across barriers).

#define BATCH 512
#define SEQ   1024
#define INP   64
#define HID   256
#define CLS   10
#define NTHREADS 512
#define TSCALE 2.8853900817779268f // 2*log2(e), folded into W_ih/b_ih

typedef short bf16x8 __attribute__((ext_vector_type(8)));
typedef float f32x4  __attribute__((ext_vector_type(4)));

static __device__ __forceinline__ unsigned short f2bf(float f) {
  __hip_bfloat16 h = __float2bfloat16(f);   // RNE
  return *reinterpret_cast<unsigned short*>(&h);
}
static __device__ __forceinline__ float bf2f(unsigned short b) {
  union { unsigned int u; float f; } v; v.u = ((unsigned int)b) << 16;
  return v.f;
}
static __device__ __forceinline__ unsigned int cvt_pk_bf16(float lo, float hi) {
  unsigned int r;
  asm("v_cvt_pk_bf16_f32 %0, %1, %2" : "=v"(r) : "v"(lo), "v"(hi));
  return r;
}
static __device__ __forceinline__ float fast_exp2(float x) {
#if __has_builtin(__builtin_amdgcn_exp2f)
  return __builtin_amdgcn_exp2f(x);
#else
  return __exp2f(x);
#endif
}
static __device__ __forceinline__ float fast_rcp(float x) {
#if __has_builtin(__builtin_amdgcn_rcpf)
  return __builtin_amdgcn_rcpf(x);
#else
  return 1.0f / x;
#endif
}
// pre-activation already scaled by 2*log2(e): tanh(x) = 1 - 2/(1 + exp2(s)).
static __device__ __forceinline__ float tanh_scaled(float s) {
  return 1.0f - 2.0f * fast_rcp(1.0f + fast_exp2(s));
}

#define MFMA16(A, B, C) __builtin_amdgcn_mfma_f32_16x16x32_bf16(A, B, C, 0, 0, 0)

// Drain LDS ops only; in-flight global x loads (vmcnt) stay pending.
#define BARRIER() asm volatile("s_waitcnt lgkmcnt(0)\n\ts_barrier" ::: "memory")

// One scan step (reads buf CUR, writes buf CUR^1, one barrier).
// aP0,aP1,aQ0,aQ1: persistent frag regs (masked lanes keep stale data,
// harmless: D rows 2-15 are padding). Chains: acc*a = even kt, acc*b = odd.
#define STEP(T, CUR, XR) do {                                                   \
    /* stage x(T+1) (in XR, loaded 2 steps ago) -> sX[CUR^1]; XR = x(T+3) */    \
    if (wave == 0) {                                                            \
      ((unsigned int*)sX[(CUR) ^ 1])[(xcp >> 4) * 32 + xrow * 16 + (xcp & 15)]  \
          = cvt_pk_bf16(XR.x, XR.y);                                            \
      int tn_ = (T) + 3; tn_ = tn_ < SEQ ? tn_ : SEQ - 1;                       \
      XR = *(const float2*)&xstage[(size_t)tn_ * INP];                          \
    }                                                                           \
    f32x4 acc0a = {bias0, bias0, bias0, bias0};                                 \
    f32x4 acc1a = {bias1, bias1, bias1, bias1};                                 \
    f32x4 acc0b = {0.f, 0.f, 0.f, 0.f};                                         \
    f32x4 acc1b = {0.f, 0.f, 0.f, 0.f};                                         \
    /* masked A-reads: only lanes frow<2 carry real rows */                     \
    if (frow < 2) {                                                             \
      aP0 = *(const bf16x8*)&sX[CUR][0][frow][g8];                              \
      aP1 = *(const bf16x8*)&sX[CUR][1][frow][g8];                              \
      aQ0 = *(const bf16x8*)&sH[CUR][0][frow][g8];                              \
      aQ1 = *(const bf16x8*)&sH[CUR][1][frow][g8];                              \
    }                                                                           \
    __builtin_amdgcn_s_setprio(1);                                              \
    acc0a = MFMA16(aP0, bw[0][0], acc0a); acc1a = MFMA16(aP0, bw[0][1], acc1a); \
    acc0b = MFMA16(aP1, bw[1][0], acc0b); acc1b = MFMA16(aP1, bw[1][1], acc1b); \
    __builtin_amdgcn_sched_barrier(0);                                          \
    if (frow < 2) {                                                             \
      aP0 = *(const bf16x8*)&sH[CUR][2][frow][g8];                              \
      aP1 = *(const bf16x8*)&sH[CUR][3][frow][g8];                              \
    }                                                                           \
    acc0a = MFMA16(aQ0, bw[2][0], acc0a); acc1a = MFMA16(aQ0, bw[2][1], acc1a); \
    acc0b = MFMA16(aQ1, bw[3][0], acc0b); acc1b = MFMA16(aQ1, bw[3][1], acc1b); \
    __builtin_amdgcn_sched_barrier(0);                                          \
    if (frow < 2) {                                                             \
      aQ0 = *(const bf16x8*)&sH[CUR][4][frow][g8];                              \
      aQ1 = *(const bf16x8*)&sH[CUR][5][frow][g8];                              \
    }                                                                           \
    acc0a = MFMA16(aP0, bw[4][0], acc0a); acc1a = MFMA16(aP0, bw[4][1], acc1a); \
    acc0b = MFMA16(aP1, bw[5][0], acc0b); acc1b = MFMA16(aP1, bw[5][1], acc1b); \
    __builtin_amdgcn_sched_barrier(0);                                          \
    if (frow < 2) {                                                             \
      aP0 = *(const bf16x8*)&sH[CUR][6][frow][g8];                              \
      aP1 = *(const bf16x8*)&sH[CUR][7][frow][g8];                              \
    }                                                                           \
    acc0a = MFMA16(aQ0, bw[6][0], acc0a); acc1a = MFMA16(aQ0, bw[6][1], acc1a); \
    acc0b = MFMA16(aQ1, bw[7][0], acc0b); acc1b = MFMA16(aQ1, bw[7][1], acc1b); \
    __builtin_amdgcn_sched_barrier(0);                                          \
    acc0a = MFMA16(aP0, bw[8][0], acc0a); acc1a = MFMA16(aP0, bw[8][1], acc1a); \
    acc0b = MFMA16(aP1, bw[9][0], acc0b); acc1b = MFMA16(aP1, bw[9][1], acc1b); \
    __builtin_amdgcn_s_setprio(0);                                              \
    /* D: col=lane&15, row=4g+j -> rows 0,1 live in g==0 lanes, j=0,1 */        \
    float t00 = tanh_scaled(acc0a[0] + acc0b[0]);  /* row0, col 32w+2f   */     \
    float t10 = tanh_scaled(acc1a[0] + acc1b[0]);  /* row0, col 32w+2f+1 */     \
    float t01 = tanh_scaled(acc0a[1] + acc0b[1]);  /* row1, col 32w+2f   */     \
    float t11 = tanh_scaled(acc1a[1] + acc1b[1]);  /* row1, col 32w+2f+1 */     \
    if (g == 0) {                                                               \
      unsigned int* hd_ = (unsigned int*)sH[(CUR) ^ 1];                         \
      hd_[wave * 32 + frow]      = cvt_pk_bf16(t00, t10);   /* row 0 */         \
      hd_[wave * 32 + 16 + frow] = cvt_pk_bf16(t01, t11);   /* row 1 */         \
    }                                                                           \
    BARRIER();                                                                  \
  } while (0)

__global__ __launch_bounds__(NTHREADS, 2)
void rnn_scan_kernel(const float* __restrict__ x,
                     const float* __restrict__ W_ih,
                     const float* __restrict__ b_ih,
                     const float* __restrict__ W_ho,
                     const float* __restrict__ b_ho,
                     float* __restrict__ out) {
  // Interleaved layout: [buf][kt][row][32 elems]. Element (r,c) of the
  // logical 2x256 h-panel lives at sH[buf][c>>5][r][c&31] (64B row-chunks).
  __shared__ __align__(16) unsigned short sH[2][8][2][32];  // 2 x 1 KB
  __shared__ __align__(16) unsigned short sX[2][2][2][32];  // 2 x 256 B

  const int tid  = threadIdx.x;
  const int lane = tid & 63;
  const int wave = tid >> 6;          // 0..7
  const int b0   = blockIdx.x * 2;    // two batch rows per block

  const int g    = (lane >> 4) & 3;   // k-group within fragment
  const int g8   = g * 8;             // element offset within k-tile chunk
  const int frow = lane & 15;         // A-row (reads) / B,D tile-col

  // ---- Preload W_ih as B-fragments (bf16, pre-scaled by TSCALE).
  // Tile q: global col = 32*wave + 2*frow + q. Lane (g,f): B[kt*32+8g+i][f].
  bf16x8 bw[10][2];
  const int colE = 32 * wave + 2 * frow;
  const float bias0 = b_ih[colE] * TSCALE;
  const float bias1 = b_ih[colE + 1] * TSCALE;
#pragma unroll
  for (int q = 0; q < 2; ++q) {
#pragma unroll
    for (int kt = 0; kt < 10; ++kt) {
      bf16x8 v;
#pragma unroll
      for (int i = 0; i < 8; ++i)
        v[i] = (short)f2bf(W_ih[(size_t)(kt * 32 + g * 8 + i) * HID + colE + q] * TSCALE);
      bw[kt][q] = v;
    }
  }

  // ---- x staging: wave 0, lane -> (row = lane>>5, col-pair = lane&31).
  const int xrow = lane >> 5, xcp = lane & 31;
  const float* xstage = x + (size_t)(b0 + xrow) * SEQ * INP + xcp * 2;
  float2 xrA = make_float2(0.f, 0.f), xrB = make_float2(0.f, 0.f);

  // ---- Persistent A-frag registers (masked lanes keep stale copies).
  bf16x8 aP0 = {}, aP1 = {}, aQ0 = {}, aQ1 = {};

  // ---- Prologue: h(0)=0; stage x(0) -> sX[0]; xrA=x(1), xrB=x(2).
  if (tid < 256) ((unsigned int*)sH[0])[tid] = 0u;
  if (wave == 0) {
    float2 v0 = *(const float2*)&xstage[0];
    ((unsigned int*)sX[0])[(xcp >> 4) * 32 + xrow * 16 + (xcp & 15)]
        = cvt_pk_bf16(v0.x, v0.y);
    xrA = *(const float2*)&xstage[(size_t)1 * INP];
    xrB = *(const float2*)&xstage[(size_t)2 * INP];
  }
  BARRIER();

  // ---- Main scan: unroll-2 -> static buffer flip + x-register rotation.
#pragma unroll 1
  for (int t = 0; t < SEQ; t += 2) {
    STEP(t,     0, xrA);
    STEP(t + 1, 1, xrB);
  }
  // SEQ even -> h_final in sH[0]

  // ---- Head: out[b0+r] = h_final @ W_ho + b_ho (2 rows x 10 cols).
  if (tid < 2 * CLS) {
    const int r = tid / CLS, cl = tid - r * CLS;
    float s = b_ho[cl];
#pragma unroll 8
    for (int k = 0; k < HID; ++k)
      s += bf2f(sH[0][k >> 5][r][k & 31]) * W_ho[(size_t)k * CLS + cl];
    out[(size_t)(b0 + r) * CLS + cl] = s;
  }
}

extern "C" void kernel_launch(void* const* d_in, const int* in_sizes, int n_in,
                              void* d_out, int out_size, void* d_ws, size_t ws_size,
                              hipStream_t stream) {
  const float* x    = (const float*)d_in[0];
  const float* W_ih = (const float*)d_in[1];
  const float* b_ih = (const float*)d_in[2];
  const float* W_ho = (const float*)d_in[3];
  const float* b_ho = (const float*)d_in[4];
  float* out = (float*)d_out;

  rnn_scan_kernel<<<BATCH / 2, NTHREADS, 0, stream>>>(x, W_ih, b_ih, W_ho, b_ho, out);
}